// Round 6
// baseline (439.208 us; speedup 1.0000x reference)
//
#include <hip/hip_runtime.h>

typedef float v4f __attribute__((ext_vector_type(4)));

#define RAD 3
#define TW  256              // tile width  (64 lanes x 4 cols)
#define TH  16               // tile height (4 waves x 4 rows, 2 rows/step)
#define LROWS (TH + 2*RAD)   // 22
#define PITCH 264            // LDS row pitch (floats); row bytes 1056 (16B-aligned)

#define LOG2E 1.4426950408889634f
#define KC2   (-50.0f * LOG2E)          // color coeff, pre-scaled by log2(e)
#define SSC   (LOG2E / 18.0f)           // spatial coeff, pre-scaled
#define SARG(dy,dx) (-(float)(((dy)-3)*((dy)-3) + ((dx)-3)*((dx)-3)) * SSC)

__device__ __forceinline__ float fexp2(float x) { return __builtin_amdgcn_exp2f(x); }

__global__ __launch_bounds__(256) void bilateral_kernel(
    const float* __restrict__ in, float* __restrict__ out, int H, int W)
{
    __shared__ float tile[LROWS * PITCH];

    const int tx = threadIdx.x;              // 0..63
    const int ty = threadIdx.y;              // 0..3 (wave id)
    const int gx0 = blockIdx.x * TW;
    const int gy0 = blockIdx.y * TH;
    const size_t plane = (size_t)blockIdx.z * H * W;
    const float* __restrict__ p = in + plane;
    float* __restrict__ q = out + plane;

    // ---- Stage 22 x 264 tile (tile col c <-> global col gx0 + c - 4) ----
    const bool xedge = (blockIdx.x == 0) || (blockIdx.x == gridDim.x - 1);
    for (int r = ty; r < LROWS; r += 4) {
        const int gy = min(max(gy0 + r - RAD, 0), H - 1);
        const float* rp = p + (size_t)gy * W;
        for (int qd = tx; qd < PITCH / 4; qd += 64) {
            const int gc = gx0 - 4 + 4 * qd;
            v4f val;
            if (!xedge || (gc >= 0 && gc + 3 < W)) {
                val = *reinterpret_cast<const v4f*>(rp + gc);
            } else {
                #pragma unroll
                for (int e = 0; e < 4; ++e) {
                    const int c = min(max(gc + e, 0), W - 1);
                    val[e] = rp[c];
                }
            }
            *reinterpret_cast<v4f*>(&tile[r * PITCH + 4 * qd]) = val;
        }
    }
    __syncthreads();

    // Each wave owns rows [4*ty, 4*ty+4); 2 steps of a vertical pixel pair.
    #pragma unroll 1
    for (int step = 0; step < 2; ++step) {
        const int ory = ty * 4 + step * 2;   // output rows ory, ory+1 (tile-relative)

        // Centers: tile rows ory+3 / ory+4, tile cols 4tx+4 .. 4tx+7
        const v4f xc0 = *reinterpret_cast<const v4f*>(&tile[(ory + 3) * PITCH + 4 * tx + 4]);
        const v4f xc1 = *reinterpret_cast<const v4f*>(&tile[(ory + 4) * PITCH + 4 * tx + 4]);

        float num0[4], den0[4], num1[4], den1[4];
        #pragma unroll
        for (int pp = 0; pp < 4; ++pp) {
            num0[pp] = 0.f; den0[pp] = 0.f;
            num1[pp] = 0.f; den1[pp] = 0.f;
        }

        // Sample row ory+rr serves center0 at dy=rr (rr<=6) and center1 at dy=rr-1 (rr>=1)
        #pragma unroll
        for (int rr = 0; rr < 8; ++rr) {
            const float* rowp = &tile[(ory + rr) * PITCH + 4 * tx];
            const v4f ra = *reinterpret_cast<const v4f*>(rowp);
            const v4f rb = *reinterpret_cast<const v4f*>(rowp + 4);
            const v4f rc = *reinterpret_cast<const v4f*>(rowp + 8);
            const float v[12] = {ra.x, ra.y, ra.z, ra.w,
                                 rb.x, rb.y, rb.z, rb.w,
                                 rc.x, rc.y, rc.z, rc.w};

            #pragma unroll
            for (int dx = 0; dx < 7; ++dx) {
                #pragma unroll
                for (int pp = 0; pp < 4; ++pp) {
                    const float s = v[1 + pp + dx];
                    if (rr < 7) {                       // center0 tap, dy = rr
                        const float d = s - xc0[pp];
                        const float u = KC2 * d;
                        const float w = fexp2(fmaf(u, d, SARG(rr, dx)));
                        num0[pp] = fmaf(w, s, num0[pp]);
                        den0[pp] += w;
                    }
                    if (rr >= 1) {                      // center1 tap, dy = rr-1
                        const float d = s - xc1[pp];
                        const float u = KC2 * d;
                        const float w = fexp2(fmaf(u, d, SARG(rr - 1, dx)));
                        num1[pp] = fmaf(w, s, num1[pp]);
                        den1[pp] += w;
                    }
                }
            }
        }

        v4f o0, o1;
        #pragma unroll
        for (int pp = 0; pp < 4; ++pp) {
            o0[pp] = num0[pp] * __builtin_amdgcn_rcpf(den0[pp]);
            o1[pp] = num1[pp] * __builtin_amdgcn_rcpf(den1[pp]);
        }
        float* q0 = q + (size_t)(gy0 + ory) * W + gx0 + 4 * tx;
        *reinterpret_cast<v4f*>(q0)     = o0;
        *reinterpret_cast<v4f*>(q0 + W) = o1;
    }
}

extern "C" void kernel_launch(void* const* d_in, const int* in_sizes, int n_in,
                              void* d_out, int out_size, void* d_ws, size_t ws_size,
                              hipStream_t stream)
{
    const float* in = (const float*)d_in[0];
    float* out = (float*)d_out;

    const int H = 1024, W = 1024;
    const int planes = in_sizes[0] / (H * W);       // 48

    dim3 grid(W / TW, H / TH, planes);              // 4 x 64 x 48
    dim3 block(64, 4, 1);
    bilateral_kernel<<<grid, block, 0, stream>>>(in, out, H, W);
}

// Round 7
// 405.585 us; speedup vs baseline: 1.0829x; 1.0829x over previous
//
#include <hip/hip_runtime.h>

#define RAD 3
#define TW  128              // tile width  (64 lanes x 2 cols)
#define TH  32               // tile height; each wave owns 8 consecutive rows
#define LROWS (TH + 2*RAD)   // 38
#define LCOLS (TW + 2*RAD)   // 134
#define PITCH 136            // LDS row pitch (floats), even -> float2-aligned windows

#define LOG2E 1.4426950408889634f
#define KC2   (-50.0f * LOG2E)          // color coeff, pre-scaled by log2(e)
#define SSC   (LOG2E / 18.0f)           // spatial coeff, pre-scaled
#define SARG(dy,dx) (-(float)(((dy)-3)*((dy)-3) + ((dx)-3)*((dx)-3)) * SSC)

__device__ __forceinline__ float fexp2(float x) { return __builtin_amdgcn_exp2f(x); }

__global__ __launch_bounds__(256) void bilateral_kernel(
    const float* __restrict__ in, float* __restrict__ out, int H, int W)
{
    __shared__ float tile[LROWS * PITCH];

    const int tx = threadIdx.x;              // 0..63
    const int ty = threadIdx.y;              // 0..3 (wave id)
    const int gx0 = blockIdx.x * TW;
    const int gy0 = blockIdx.y * TH;
    const size_t plane = (size_t)blockIdx.z * H * W;
    const float* __restrict__ p = in + plane;
    float* __restrict__ q = out + plane;

    // ---- Stage 38 x 134 tile; tile col c <-> global col gx0 + c - 3 ----
    for (int r = ty; r < LROWS; r += 4) {
        const int gy = min(max(gy0 + r - RAD, 0), H - 1);
        const float* rp = p + (size_t)gy * W;
        for (int c = tx; c < LCOLS; c += 64) {
            const int g = min(max(gx0 + c - RAD, 0), W - 1);
            tile[r * PITCH + c] = rp[g];
        }
    }
    __syncthreads();

    // Each thread: output cols gx0+2tx, gx0+2tx+1 (tile cols 2tx+3, 2tx+4),
    // 8 rows sequentially. Window per sample row: tile cols [2tx, 2tx+7].
    #pragma unroll 1
    for (int j = 0; j < 8; ++j) {
        const int orow = ty * 8 + j;         // tile-relative output row 0..31

        const float xc0 = tile[(orow + 3) * PITCH + 2 * tx + 3];
        const float xc1 = tile[(orow + 3) * PITCH + 2 * tx + 4];
        // center taps (w == 1 exactly) folded into init; loop skips them
        float num0 = xc0, den0 = 1.0f;
        float num1 = xc1, den1 = 1.0f;

        #pragma unroll
        for (int rr = 0; rr < 7; ++rr) {
            const float* wp = &tile[(orow + rr) * PITCH + 2 * tx];
            const float2 w01 = *reinterpret_cast<const float2*>(wp);
            const float2 w23 = *reinterpret_cast<const float2*>(wp + 2);
            const float2 w45 = *reinterpret_cast<const float2*>(wp + 4);
            const float2 w67 = *reinterpret_cast<const float2*>(wp + 6);
            const float w[8] = {w01.x, w01.y, w23.x, w23.y,
                                w45.x, w45.y, w67.x, w67.y};

            #pragma unroll
            for (int dx = 0; dx < 7; ++dx) {
                if (!(rr == 3 && dx == 3)) {        // skip exact center taps
                    {   // pixel 0: center tile col 2tx+3, sample w[dx]
                        const float s = w[dx];
                        const float d = s - xc0;
                        const float u = KC2 * d;
                        const float e = fexp2(fmaf(u, d, SARG(rr, dx)));
                        num0 = fmaf(e, s, num0);
                        den0 += e;
                    }
                    {   // pixel 1: center tile col 2tx+4, sample w[dx+1]
                        const float s = w[dx + 1];
                        const float d = s - xc1;
                        const float u = KC2 * d;
                        const float e = fexp2(fmaf(u, d, SARG(rr, dx)));
                        num1 = fmaf(e, s, num1);
                        den1 += e;
                    }
                }
            }
        }

        float2 o;
        o.x = num0 * __builtin_amdgcn_rcpf(den0);
        o.y = num1 * __builtin_amdgcn_rcpf(den1);
        *reinterpret_cast<float2*>(q + (size_t)(gy0 + orow) * W + gx0 + 2 * tx) = o;
    }
}

extern "C" void kernel_launch(void* const* d_in, const int* in_sizes, int n_in,
                              void* d_out, int out_size, void* d_ws, size_t ws_size,
                              hipStream_t stream)
{
    const float* in = (const float*)d_in[0];
    float* out = (float*)d_out;

    const int H = 1024, W = 1024;
    const int planes = in_sizes[0] / (H * W);       // 48

    dim3 grid(W / TW, H / TH, planes);              // 8 x 32 x 48
    dim3 block(64, 4, 1);
    bilateral_kernel<<<grid, block, 0, stream>>>(in, out, H, W);
}

// Round 8
// 379.681 us; speedup vs baseline: 1.1568x; 1.0682x over previous
//
#include <hip/hip_runtime.h>

typedef float v4f __attribute__((ext_vector_type(4)));

#define RAD 3
#define TW  256              // tile width  (64 lanes x 4 cols)
#define TH  16               // tile height (4 waves x 4 rows, 2 steps of row-pair)
#define LROWS (TH + 2*RAD)   // 22
#define PITCH 264            // LDS row pitch (floats); 1056 B, b128-aligned

#define LOG2E 1.4426950408889634f
#define KC2   (-50.0f * LOG2E)          // color coeff, pre-scaled by log2(e)

__device__ __forceinline__ float fexp2(float x) { return __builtin_amdgcn_exp2f(x); }

// Spatial weights exp(-((dy-3)^2+(dx-3)^2)/18) as compile-time literals.
__device__ __forceinline__ constexpr float wsv(int k) {
    return k == 0  ? 1.0f :
           k == 1  ? 0.9459594f :
           k == 2  ? 0.8948393f :
           k == 4  ? 0.8007374f :
           k == 5  ? 0.7574660f :
           k == 8  ? 0.6411804f :
           k == 9  ? 0.6065307f :
           k == 10 ? 0.5737534f :
           k == 13 ? 0.4856716f :
                     0.3678794f;   // k == 18
}
#define WS(dy,dx) wsv(((dy)-3)*((dy)-3) + ((dx)-3)*((dx)-3))

__global__ __launch_bounds__(256) void bilateral_kernel(
    const float* __restrict__ in, float* __restrict__ out, int H, int W)
{
    __shared__ float tile[LROWS * PITCH];

    const int tx = threadIdx.x;              // 0..63
    const int ty = threadIdx.y;              // 0..3 (wave id)
    const int gx0 = blockIdx.x * TW;
    const int gy0 = blockIdx.y * TH;
    const size_t plane = (size_t)blockIdx.z * H * W;
    const float* __restrict__ p = in + plane;
    float* __restrict__ q = out + plane;

    // ---- Stage 22 x 264 tile (tile col c <-> global col gx0 + c - 4) ----
    const bool xedge = (blockIdx.x == 0) || (blockIdx.x == gridDim.x - 1);
    for (int r = ty; r < LROWS; r += 4) {
        const int gy = min(max(gy0 + r - RAD, 0), H - 1);
        const float* rp = p + (size_t)gy * W;
        for (int qd = tx; qd < PITCH / 4; qd += 64) {
            const int gc = gx0 - 4 + 4 * qd;
            v4f val;
            if (!xedge || (gc >= 0 && gc + 3 < W)) {
                val = *reinterpret_cast<const v4f*>(rp + gc);
            } else {
                #pragma unroll
                for (int e = 0; e < 4; ++e) {
                    const int c = min(max(gc + e, 0), W - 1);
                    val[e] = rp[c];
                }
            }
            *reinterpret_cast<v4f*>(&tile[r * PITCH + 4 * qd]) = val;
        }
    }
    __syncthreads();

    // Each wave owns rows [4*ty, 4*ty+4); 2 steps of a vertical pixel pair.
    #pragma unroll 1
    for (int step = 0; step < 2; ++step) {
        const int ory = ty * 4 + step * 2;   // output rows ory, ory+1 (tile-relative)

        // Centers: tile rows ory+3 / ory+4, tile cols 4tx+4 .. 4tx+7
        const v4f xc0 = *reinterpret_cast<const v4f*>(&tile[(ory + 3) * PITCH + 4 * tx + 4]);
        const v4f xc1 = *reinterpret_cast<const v4f*>(&tile[(ory + 4) * PITCH + 4 * tx + 4]);

        // Weight-scale cancellation: w~ = exp2(KC2*s^2 - 2*KC2*x*s)
        //   = exp2(fma(m, p, rt)) with m = -2x (per center), p = KC2*s, rt = p*s.
        // Scale exp2(-KC2*x^2) is common to num/den and cancels in the ratio.
        float m0[4], m1[4], num0[4], den0[4], num1[4], den1[4];
        #pragma unroll
        for (int pp = 0; pp < 4; ++pp) {
            m0[pp] = -2.0f * xc0[pp];
            m1[pp] = -2.0f * xc1[pp];
            num0[pp] = 0.f; den0[pp] = 0.f;
            num1[pp] = 0.f; den1[pp] = 0.f;
        }

        // Sample row ory+rr serves center0 at dy=rr (rr<=6), center1 at dy=rr-1 (rr>=1)
        #pragma unroll
        for (int rr = 0; rr < 8; ++rr) {
            const float* rowp = &tile[(ory + rr) * PITCH + 4 * tx];
            const v4f ra = *reinterpret_cast<const v4f*>(rowp);
            const v4f rb = *reinterpret_cast<const v4f*>(rowp + 4);
            const v4f rc = *reinterpret_cast<const v4f*>(rowp + 8);
            const float v[12] = {ra.x, ra.y, ra.z, ra.w,
                                 rb.x, rb.y, rb.z, rb.w,
                                 rc.x, rc.y, rc.z, rc.w};

            #pragma unroll
            for (int k = 1; k <= 10; ++k) {       // window sample index
                const float s  = v[k];
                const float pk = KC2 * s;         // VOP2 literal mul
                const float rt = pk * s;

                #pragma unroll
                for (int pp = 0; pp < 4; ++pp) {
                    const int dx = k - 1 - pp;    // compile-time
                    if (dx < 0 || dx > 6) continue;

                    if (rr < 7) {                 // center0 tap, dy = rr
                        const float a = fmaf(m0[pp], pk, rt);
                        const float e = fexp2(a);
                        const float w = (WS(rr, dx) == 1.0f) ? e : WS(rr, dx) * e;
                        num0[pp] = fmaf(w, s, num0[pp]);
                        den0[pp] += w;
                    }
                    if (rr >= 1) {                // center1 tap, dy = rr-1
                        const float a = fmaf(m1[pp], pk, rt);
                        const float e = fexp2(a);
                        const float w = (WS(rr - 1, dx) == 1.0f) ? e : WS(rr - 1, dx) * e;
                        num1[pp] = fmaf(w, s, num1[pp]);
                        den1[pp] += w;
                    }
                }
            }
        }

        v4f o0, o1;
        #pragma unroll
        for (int pp = 0; pp < 4; ++pp) {
            o0[pp] = num0[pp] * __builtin_amdgcn_rcpf(den0[pp]);
            o1[pp] = num1[pp] * __builtin_amdgcn_rcpf(den1[pp]);
        }
        float* q0 = q + (size_t)(gy0 + ory) * W + gx0 + 4 * tx;
        *reinterpret_cast<v4f*>(q0)     = o0;
        *reinterpret_cast<v4f*>(q0 + W) = o1;
    }
}

extern "C" void kernel_launch(void* const* d_in, const int* in_sizes, int n_in,
                              void* d_out, int out_size, void* d_ws, size_t ws_size,
                              hipStream_t stream)
{
    const float* in = (const float*)d_in[0];
    float* out = (float*)d_out;

    const int H = 1024, W = 1024;
    const int planes = in_sizes[0] / (H * W);       // 48

    dim3 grid(W / TW, H / TH, planes);              // 4 x 64 x 48
    dim3 block(64, 4, 1);
    bilateral_kernel<<<grid, block, 0, stream>>>(in, out, H, W);
}

// Round 9
// 308.860 us; speedup vs baseline: 1.4220x; 1.2293x over previous
//
#include <hip/hip_runtime.h>

typedef float v4f __attribute__((ext_vector_type(4)));

#define RAD 3
#define TW  256              // tile width  (64 lanes x 4 cols)
#define TH  16               // tile height (4 waves x 4 rows, 2 steps of row-pair)
#define LROWS (TH + 2*RAD)   // 22
#define PITCH 264            // LDS row pitch (floats); 1056 B, b128-aligned

#define LOG2E 1.4426950408889634f
// color coefficient pre-scaled into fast-exp integer domain: -50*log2(e)*2^23
#define KC2_23 (-50.0f * LOG2E * 8388608.0f)

// Fast-exp2 magic per tap position, folding: exponent bias (127), balanced
// piecewise-linear error offset (-0.0425 in log2), and the spatial weight
// log2(ws) = -k/(18*ln2), k = (dy-3)^2+(dx-3)^2.   All compile-time.
__device__ __forceinline__ constexpr float MAGIC(int dy, int dx) {
    const int k = (dy - 3) * (dy - 3) + (dx - 3) * (dx - 3);
    return (127.0f - 0.0425f - (float)k * 0.08014973f) * 8388608.0f;
}

// w = ws * 2^(KC2*d*d):  t = KC2_23*d;  y = fma(t, d, M);  w = bits(int(y)).
// y in [4.5e8, 1.07e9]: always positive, < 2^31, result always normal f32.
__device__ __forceinline__ float fastw(float d, float M) {
    const float t = KC2_23 * d;
    const float y = fmaf(t, d, M);
    return __int_as_float((int)y);
}

__global__ __launch_bounds__(256) void bilateral_kernel(
    const float* __restrict__ in, float* __restrict__ out, int H, int W)
{
    __shared__ float tile[LROWS * PITCH];

    const int tx = threadIdx.x;              // 0..63
    const int ty = threadIdx.y;              // 0..3 (wave id)
    const int gx0 = blockIdx.x * TW;
    const int gy0 = blockIdx.y * TH;
    const size_t plane = (size_t)blockIdx.z * H * W;
    const float* __restrict__ p = in + plane;
    float* __restrict__ q = out + plane;

    // ---- Stage 22 x 264 tile (tile col c <-> global col gx0 + c - 4) ----
    const bool xedge = (blockIdx.x == 0) || (blockIdx.x == gridDim.x - 1);
    for (int r = ty; r < LROWS; r += 4) {
        const int gy = min(max(gy0 + r - RAD, 0), H - 1);
        const float* rp = p + (size_t)gy * W;
        for (int qd = tx; qd < PITCH / 4; qd += 64) {
            const int gc = gx0 - 4 + 4 * qd;
            v4f val;
            if (!xedge || (gc >= 0 && gc + 3 < W)) {
                val = *reinterpret_cast<const v4f*>(rp + gc);
            } else {
                #pragma unroll
                for (int e = 0; e < 4; ++e) {
                    const int c = min(max(gc + e, 0), W - 1);
                    val[e] = rp[c];
                }
            }
            *reinterpret_cast<v4f*>(&tile[r * PITCH + 4 * qd]) = val;
        }
    }
    __syncthreads();

    // Each wave owns rows [4*ty, 4*ty+4); 2 steps of a vertical pixel pair.
    #pragma unroll 1
    for (int step = 0; step < 2; ++step) {
        const int ory = ty * 4 + step * 2;   // output rows ory, ory+1 (tile-relative)

        // Centers: tile rows ory+3 / ory+4, tile cols 4tx+4 .. 4tx+7
        const v4f xc0 = *reinterpret_cast<const v4f*>(&tile[(ory + 3) * PITCH + 4 * tx + 4]);
        const v4f xc1 = *reinterpret_cast<const v4f*>(&tile[(ory + 4) * PITCH + 4 * tx + 4]);

        float num0[4], den0[4], num1[4], den1[4];
        #pragma unroll
        for (int pp = 0; pp < 4; ++pp) {
            num0[pp] = 0.f; den0[pp] = 0.f;
            num1[pp] = 0.f; den1[pp] = 0.f;
        }

        // Sample row ory+rr serves center0 at dy=rr (rr<=6), center1 at dy=rr-1 (rr>=1)
        #pragma unroll
        for (int rr = 0; rr < 8; ++rr) {
            const float* rowp = &tile[(ory + rr) * PITCH + 4 * tx];
            const v4f ra = *reinterpret_cast<const v4f*>(rowp);
            const v4f rb = *reinterpret_cast<const v4f*>(rowp + 4);
            const v4f rc = *reinterpret_cast<const v4f*>(rowp + 8);
            const float v[12] = {ra.x, ra.y, ra.z, ra.w,
                                 rb.x, rb.y, rb.z, rb.w,
                                 rc.x, rc.y, rc.z, rc.w};

            #pragma unroll
            for (int dx = 0; dx < 7; ++dx) {
                #pragma unroll
                for (int pp = 0; pp < 4; ++pp) {
                    const float s = v[1 + pp + dx];
                    if (rr < 7) {                       // center0 tap, dy = rr
                        const float w = fastw(s - xc0[pp], MAGIC(rr, dx));
                        num0[pp] = fmaf(w, s, num0[pp]);
                        den0[pp] += w;
                    }
                    if (rr >= 1) {                      // center1 tap, dy = rr-1
                        const float w = fastw(s - xc1[pp], MAGIC(rr - 1, dx));
                        num1[pp] = fmaf(w, s, num1[pp]);
                        den1[pp] += w;
                    }
                }
            }
        }

        v4f o0, o1;
        #pragma unroll
        for (int pp = 0; pp < 4; ++pp) {
            o0[pp] = num0[pp] * __builtin_amdgcn_rcpf(den0[pp]);
            o1[pp] = num1[pp] * __builtin_amdgcn_rcpf(den1[pp]);
        }
        float* q0 = q + (size_t)(gy0 + ory) * W + gx0 + 4 * tx;
        *reinterpret_cast<v4f*>(q0)     = o0;
        *reinterpret_cast<v4f*>(q0 + W) = o1;
    }
}

extern "C" void kernel_launch(void* const* d_in, const int* in_sizes, int n_in,
                              void* d_out, int out_size, void* d_ws, size_t ws_size,
                              hipStream_t stream)
{
    const float* in = (const float*)d_in[0];
    float* out = (float*)d_out;

    const int H = 1024, W = 1024;
    const int planes = in_sizes[0] / (H * W);       // 48

    dim3 grid(W / TW, H / TH, planes);              // 4 x 64 x 48
    dim3 block(64, 4, 1);
    bilateral_kernel<<<grid, block, 0, stream>>>(in, out, H, W);
}